// Round 9
// baseline (130.851 us; speedup 1.0000x reference)
//
#include <hip/hip_runtime.h>

#define BEVN 100
#define NB 8
#define NC 512
#define FH 88
#define FW 176
#define HWSZ (FH * FW)          // 15488 pixels per channel slice
#define NG4  (HWSZ / 4)
#define G4PR (FW / 4)           // 44 uint4-groups per image row
#define NPAIR (BEVN * BEVN / 2) // 5000 cell-pairs
#define PSPLIT 2500             // pairs with p>=2500 <=> BEV row i>=50 (far)
#define NCONS 896               // 14 waves: far-cell consumers
#define NPROD 128               // 2 waves: listB producers

typedef float    f32x4 __attribute__((ext_vector_type(4)));
typedef float    f32x2 __attribute__((ext_vector_type(2)));
typedef unsigned u32x4 __attribute__((ext_vector_type(4)));

// R7 structure (block = (b, channel-pair), marked-row staging, bf16 2-ch pack)
// + row-disjoint in-buffer producer/consumer: far cells (i>=50) need only a
// narrow horizon band (listA, staged up front); while 14 waves compute far
// cells, 2 waves stage the near-only rows (listB) into disjoint rows of the
// SAME buffer. Near cells computed by all waves afterwards (with plane-skip).
__device__ __forceinline__ unsigned bf16rne(float f) {
    const unsigned b = __float_as_uint(f);
    return (b + 0x7fffu + ((b >> 16) & 1u)) >> 16;   // round-nearest-even
}
__device__ __forceinline__ float lo16f(unsigned u) { return __uint_as_float(u << 16); }
__device__ __forceinline__ float hi16f(unsigned u) { return __uint_as_float(u & 0xffff0000u); }

__global__ __launch_bounds__(1024, 8)
void vt_kernel(const float* __restrict__ img,
               const float* __restrict__ intr,
               const int* __restrict__ p_imw,
               const int* __restrict__ p_imh,
               float* __restrict__ out)
{
    __shared__ unsigned      buf[HWSZ];      // packed {bf16 c0 | bf16 c1<<16}
    __shared__ float4        ytab[BEVN * 3]; // {wy0/3, wy1/3, rowbase0, rowbase1}
    __shared__ unsigned char markA[FH];      // rows needed by far cells (i>=50)
    __shared__ unsigned char markN[FH];      // rows needed by near cells
    __shared__ short         mlistA[FH], mlistB[FH];
    __shared__ int           ngA_sh, ngB_sh;

    const int blk = blockIdx.x;         // b*256 + cpair
    const int b   = blk >> 8;
    const int bc0 = b * NC + (blk & 255) * 2;
    const int tid = (int)threadIdx.x;

    const float fx  = intr[b * 9 + 0];
    const float cxv = intr[b * 9 + 2];
    const float fy  = intr[b * 9 + 4];
    const float cyv = intr[b * 9 + 5];
    const float wsc = (float)FW / (float)p_imw[0];   // 0.25
    const float hsc = (float)FH / (float)p_imh[0];   // 0.25

    if (tid < FH) { markA[tid] = 0; markN[tid] = 0; }
    __syncthreads();

    // ---- ytab + far/near row marking + zero-fill buffer ----
    if (tid < BEVN * 3) {
        const int   i  = tid / 3;
        const int   k  = tid - 3 * i;
        const float z  = 0.125f + 0.5f * (float)i;
        const float iz = 1.0f / z;
        const float yk = (k == 0) ? -1.0f : ((k == 1) ? 0.5f : 2.0f);
        const float yp = fmaf(fy * yk * iz + cyv, hsc, -0.5f);
        const float yf = floorf(yp);
        const int   y0 = (int)yf;
        float wy1 = yp - yf;
        float wy0 = 1.0f - wy1;
        wy0 = ((unsigned)y0 < (unsigned)FH) ? wy0 : 0.0f;
        wy1 = ((unsigned)(y0 + 1) < (unsigned)FH) ? wy1 : 0.0f;
        unsigned char* mk = (i >= 50) ? markA : markN;
        if (wy0 != 0.0f) mk[y0] = 1;
        if (wy1 != 0.0f) mk[y0 + 1] = 1;
        const int yb0 = min(max(y0, 0), FH - 1) * FW;
        const int yb1 = min(max(y0 + 1, 0), FH - 1) * FW;
        float4 e;
        e.x = wy0 * (1.0f / 3.0f);
        e.y = wy1 * (1.0f / 3.0f);
        e.z = __int_as_float(yb0);
        e.w = __int_as_float(yb1);
        ytab[tid] = e;
    }
    {   // zero-fill (unstaged rows read 0.0 with weight 0)
        const u32x4 zz = {0u, 0u, 0u, 0u};
        u32x4* l4 = (u32x4*)buf;
        #pragma unroll
        for (int q = 0; q < 4; ++q) {
            const int g = tid + q * 1024;
            if (g < NG4) l4[g] = zz;
        }
    }
    __syncthreads();

    if (tid == 0) {     // compact: listA = far rows; listB = near-only rows
        int nA = 0, nB = 0;
        for (int r = 0; r < FH; ++r) {
            if (markA[r]) mlistA[nA++] = (short)r;
            else if (markN[r]) mlistB[nB++] = (short)r;
        }
        ngA_sh = nA * G4PR;
        ngB_sh = nB * G4PR;
    }
    __syncthreads();

    const f32x4* __restrict__ s0 = (const f32x4*)(img + (size_t)bc0 * HWSZ);
    const f32x4* __restrict__ s1 = s0 + NG4;
    u32x4* l4 = (u32x4*)buf;

    // staging helper: fill rows of `list` for group-indices [base, ng) step stride
    auto stage = [&](const short* list, int ng, int base, int stride) {
        #pragma unroll 2
        for (int idx = base; idx < ng; idx += stride) {
            const int r = idx / G4PR;
            const int c = idx - r * G4PR;
            const int g = (int)list[r] * G4PR + c;
            const f32x4 a  = __builtin_nontemporal_load(s0 + g);
            const f32x4 bb = __builtin_nontemporal_load(s1 + g);
            u32x4 u;
            u.x = bf16rne(a.x) | (bf16rne(bb.x) << 16);
            u.y = bf16rne(a.y) | (bf16rne(bb.y) << 16);
            u.z = bf16rne(a.z) | (bf16rne(bb.z) << 16);
            u.w = bf16rne(a.w) | (bf16rne(bb.w) << 16);
            l4[g] = u;
        }
    };

    // x-projection: xpix = a_j * invz + bx
    const float axs = 0.5f * fx * wsc;
    const float axb = -24.875f * fx * wsc;
    const float bx  = fmaf(cxv, wsc, -0.5f);

    float* __restrict__ op0 = out + (size_t)bc0 * (BEVN * BEVN);
    float* __restrict__ op1 = op0 + (BEVN * BEVN);

    // compute helper over pair range [p0, p1), threads base..base+stride
    auto compute = [&](int p0, int p1, int base, int stride) {
        for (int p = p0 + base; p < p1; p += stride) {
            const int i  = p / 50;
            const int jp = p - 50 * i;
            const float z    = fmaf(0.5f, (float)i, 0.125f);
            const float invz = __builtin_amdgcn_rcpf(z);

            int   xb[2];
            float w0[2], w1[2];
            #pragma unroll
            for (int e = 0; e < 2; ++e) {
                const float aj   = fmaf((float)(2 * jp + e), axs, axb);
                const float xpix = fmaf(aj, invz, bx);
                const float f    = floorf(xpix);
                const int   x0   = (int)f;
                float wx1 = xpix - f;
                float wx0 = 1.0f - wx1;
                wx0 = ((unsigned)x0 < (unsigned)FW) ? wx0 : 0.0f;
                wx1 = ((unsigned)(x0 + 1) < (unsigned)FW) ? wx1 : 0.0f;
                const int xbe = min(max(x0, 0), FW - 2);
                const int d   = x0 - xbe;
                w0[e] = (d == 0) ? wx0 : ((d < 0) ? wx1 : 0.0f);
                w1[e] = (d == 0) ? wx1 : ((d < 0) ? 0.0f : wx0);
                xb[e] = xbe;
            }

            f32x2 rA, rB;
            const float wsum = (w0[0] + w1[0]) + (w0[1] + w1[1]);
            if (wsum == 0.0f) {
                rA = (f32x2){0.0f, 0.0f};
                rB = (f32x2){0.0f, 0.0f};
            } else {
                float accA[2] = {0.0f, 0.0f};
                float accB[2] = {0.0f, 0.0f};
                #pragma unroll
                for (int k = 0; k < 3; ++k) {
                    const float4 e4 = ytab[i * 3 + k];
                    if (e4.x != 0.0f || e4.y != 0.0f) {   // plane-skip (near rows)
                        const int yb0 = __float_as_int(e4.z);
                        const int yb1 = __float_as_int(e4.w);
                        #pragma unroll
                        for (int e = 0; e < 2; ++e) {
                            const unsigned* r0 = buf + (yb0 + xb[e]);
                            const unsigned* r1 = buf + (yb1 + xb[e]);
                            const unsigned u00 = r0[0], u01 = r0[1];   // ds_read2_b32
                            const unsigned u10 = r1[0], u11 = r1[1];   // ds_read2_b32
                            const float h0a = fmaf(w1[e], lo16f(u01), w0[e] * lo16f(u00));
                            const float h1a = fmaf(w1[e], lo16f(u11), w0[e] * lo16f(u10));
                            accA[e] = fmaf(e4.x, h0a, accA[e]);
                            accA[e] = fmaf(e4.y, h1a, accA[e]);
                            const float h0b = fmaf(w1[e], hi16f(u01), w0[e] * hi16f(u00));
                            const float h1b = fmaf(w1[e], hi16f(u11), w0[e] * hi16f(u10));
                            accB[e] = fmaf(e4.x, h0b, accB[e]);
                            accB[e] = fmaf(e4.y, h1b, accB[e]);
                        }
                    }
                }
                rA = (f32x2){accA[0], accA[1]};
                rB = (f32x2){accB[0], accB[1]};
            }
            __builtin_nontemporal_store(rA, (f32x2*)(op0 + 2 * p));
            __builtin_nontemporal_store(rB, (f32x2*)(op1 + 2 * p));
        }
    };

    // ---- phase 1: all threads stage listA (far rows, ~30KB) ----
    stage(mlistA, ngA_sh, tid, 1024);
    __syncthreads();

    // ---- phase 2: 14 waves compute far cells; 2 waves stage listB ----
    if (tid < NCONS) {
        compute(PSPLIT, NPAIR, tid, NCONS);
    } else {
        stage(mlistB, ngB_sh, tid - NCONS, NPROD);
    }
    __syncthreads();

    // ---- phase 3: all threads compute near cells ----
    compute(0, PSPLIT, tid, 1024);
}

extern "C" void kernel_launch(void* const* d_in, const int* in_sizes, int n_in,
                              void* d_out, int out_size, void* d_ws, size_t ws_size,
                              hipStream_t stream) {
    const float* img  = (const float*)d_in[0];
    const float* intr = (const float*)d_in[1];
    const int*   imw  = (const int*)d_in[2];
    const int*   imh  = (const int*)d_in[3];
    float*       out  = (float*)d_out;

    dim3 grid(NB * NC / 2);   // one block per (b, channel-pair)
    dim3 block(1024);
    hipLaunchKernelGGL(vt_kernel, grid, block, 0, stream,
                       img, intr, imw, imh, out);
}

// Round 10
// 105.474 us; speedup vs baseline: 1.2406x; 1.2406x over previous
//
#include <hip/hip_runtime.h>

#define BEVN 100
#define NB 8
#define NC 512
#define FH 88
#define FW 176
#define HWSZ (FH * FW)          // 15488 pixels per channel slice
#define HWU32 (HWSZ / 2)        // 7744 packed u32 (2 px each)
#define NG4  (HWSZ / 4)         // 3872 f32x4 groups per slice
#define G4PR (FW / 4)           // 44 groups per image row
#define NPAIR (BEVN * BEVN / 2) // 5000 cell-pairs

typedef float    f32x4 __attribute__((ext_vector_type(4)));
typedef float    f32x2 __attribute__((ext_vector_type(2)));
typedef unsigned u32x2 __attribute__((ext_vector_type(2)));

// One 512-thread block per (b,c); FOUR blocks resident per CU (the lever:
// R5/R8 1 barrier-domain/CU = 92-100us, R2-R7 2 domains = 82-91us -> 4
// domains absorb stage-barrier stalls via TLP). LDS: one channel packed as
// bf16 pixel-PAIRS (u32 = {px even | px odd<<16}), 31KB + ytab 4.8KB = 36KB.
// Marked-row staging (R7 win: fetch 254->140MB). Math identical to R7.
__device__ __forceinline__ unsigned bf16rne(float f) {
    const unsigned b = __float_as_uint(f);
    return (b + 0x7fffu + ((b >> 16) & 1u)) >> 16;   // round-nearest-even
}

__global__ __launch_bounds__(512, 8)
void vt_kernel(const float* __restrict__ img,
               const float* __restrict__ intr,
               const int* __restrict__ p_imw,
               const int* __restrict__ p_imh,
               float* __restrict__ out)
{
    __shared__ unsigned      bufp[HWU32 + 1]; // +1 pad: corner m+1 read
    __shared__ float4        ytab[BEVN * 3];  // {wy0/3, wy1/3, rowbase0, rowbase1}
    __shared__ unsigned char marked[FH];

    const int bc  = blockIdx.x;       // b*512 + c
    const int b   = bc >> 9;
    const int tid = (int)threadIdx.x;

    const float fx  = intr[b * 9 + 0];
    const float cxv = intr[b * 9 + 2];
    const float fy  = intr[b * 9 + 4];
    const float cyv = intr[b * 9 + 5];
    const float wsc = (float)FW / (float)p_imw[0];   // 0.25
    const float hsc = (float)FH / (float)p_imh[0];   // 0.25

    if (tid < FH) marked[tid] = 0;
    if (tid == 0) bufp[HWU32] = 0;
    __syncthreads();

    // ---- ytab + row marking (same arithmetic -> provably consistent) ----
    if (tid < BEVN * 3) {
        const int   i  = tid / 3;
        const int   k  = tid - 3 * i;
        const float z  = 0.125f + 0.5f * (float)i;
        const float iz = 1.0f / z;
        const float yk = (k == 0) ? -1.0f : ((k == 1) ? 0.5f : 2.0f);
        const float yp = fmaf(fy * yk * iz + cyv, hsc, -0.5f);
        const float yf = floorf(yp);
        const int   y0 = (int)yf;
        float wy1 = yp - yf;
        float wy0 = 1.0f - wy1;
        wy0 = ((unsigned)y0 < (unsigned)FH) ? wy0 : 0.0f;
        wy1 = ((unsigned)(y0 + 1) < (unsigned)FH) ? wy1 : 0.0f;
        if (wy0 != 0.0f) marked[y0] = 1;
        if (wy1 != 0.0f) marked[y0 + 1] = 1;
        const int yb0 = min(max(y0, 0), FH - 1) * FW;
        const int yb1 = min(max(y0 + 1, 0), FH - 1) * FW;
        float4 e;
        e.x = wy0 * (1.0f / 3.0f);
        e.y = wy1 * (1.0f / 3.0f);
        e.z = __int_as_float(yb0);
        e.w = __int_as_float(yb1);
        ytab[tid] = e;
    }
    __syncthreads();

    // ---- stage: marked rows -> packed bf16 pixel-pairs; others zeroed ----
    {
        const f32x4* __restrict__ s0 = (const f32x4*)(img + (size_t)bc * HWSZ);
        #pragma unroll
        for (int q = 0; q < 8; ++q) {
            const int g = tid + q * 512;
            if (g < NG4) {
                u32x2 u = {0u, 0u};
                const int row = g / G4PR;          // near-wave-uniform branch
                if (marked[row]) {
                    const f32x4 a = __builtin_nontemporal_load(s0 + g);
                    u.x = bf16rne(a.x) | (bf16rne(a.y) << 16);
                    u.y = bf16rne(a.z) | (bf16rne(a.w) << 16);
                }
                *(u32x2*)(bufp + 2 * g) = u;       // ds_write_b64, 8B aligned
            }
        }
    }
    __syncthreads();

    // x-projection: xpix = a_j * invz + bx
    const float axs = 0.5f * fx * wsc;
    const float axb = -24.875f * fx * wsc;
    const float bx  = fmaf(cxv, wsc, -0.5f);

    float* __restrict__ op = out + (size_t)bc * (BEVN * BEVN);

    for (int p = tid; p < NPAIR; p += 512) {
        const int i  = p / 50;               // BEV row
        const int jp = p - 50 * i;           // pair index in row
        const float z    = fmaf(0.5f, (float)i, 0.125f);
        const float invz = __builtin_amdgcn_rcpf(z);

        int   xb[2], sel[2];
        float w0[2], w1[2];
        #pragma unroll
        for (int e = 0; e < 2; ++e) {
            const float aj   = fmaf((float)(2 * jp + e), axs, axb);
            const float xpix = fmaf(aj, invz, bx);
            const float f    = floorf(xpix);
            const int   x0   = (int)f;
            float wx1 = xpix - f;
            float wx0 = 1.0f - wx1;
            wx0 = ((unsigned)x0 < (unsigned)FW) ? wx0 : 0.0f;
            wx1 = ((unsigned)(x0 + 1) < (unsigned)FW) ? wx1 : 0.0f;
            const int xbe = min(max(x0, 0), FW - 2);
            const int d   = x0 - xbe;        // 0: normal; <0: clamped up; >0: clamped down
            w0[e]  = (d == 0) ? wx0 : ((d < 0) ? wx1 : 0.0f);
            w1[e]  = (d == 0) ? wx1 : ((d < 0) ? 0.0f : wx0);
            xb[e]  = xbe;
            sel[e] = xbe & 1;                // pair straddles words when odd
        }

        f32x2 res;
        const float wsum = (w0[0] + w1[0]) + (w0[1] + w1[1]);
        if (wsum == 0.0f) {
            res = (f32x2){0.0f, 0.0f};       // whole pair OOB in x (coherent skip)
        } else {
            float acc[2] = {0.0f, 0.0f};
            #pragma unroll
            for (int k = 0; k < 3; ++k) {
                const float4 e4  = ytab[i * 3 + k];
                const int    yb0 = __float_as_int(e4.z);   // row*FW (even)
                const int    yb1 = __float_as_int(e4.w);
                #pragma unroll
                for (int e = 0; e < 2; ++e) {
                    const int m0 = (yb0 + xb[e]) >> 1;
                    const int m1 = (yb1 + xb[e]) >> 1;
                    const unsigned a0 = bufp[m0], a1 = bufp[m0 + 1];  // ds_read2_b32
                    const unsigned b0 = bufp[m1], b1 = bufp[m1 + 1];  // ds_read2_b32
                    // select the (px, px+1) halves by parity, unpack bf16 via <<16
                    const unsigned ta = a0 >> 16;
                    const float p00 = __uint_as_float((sel[e] ? ta : a0) << 16);
                    const float p01 = __uint_as_float((sel[e] ? a1 : ta) << 16);
                    const unsigned tb = b0 >> 16;
                    const float p10 = __uint_as_float((sel[e] ? tb : b0) << 16);
                    const float p11 = __uint_as_float((sel[e] ? b1 : tb) << 16);
                    const float h0 = fmaf(w1[e], p01, w0[e] * p00);
                    const float h1 = fmaf(w1[e], p11, w0[e] * p10);
                    acc[e] = fmaf(e4.x, h0, acc[e]);
                    acc[e] = fmaf(e4.y, h1, acc[e]);
                }
            }
            res = (f32x2){acc[0], acc[1]};
        }
        __builtin_nontemporal_store(res, (f32x2*)(op + 2 * p));
    }
}

extern "C" void kernel_launch(void* const* d_in, const int* in_sizes, int n_in,
                              void* d_out, int out_size, void* d_ws, size_t ws_size,
                              hipStream_t stream) {
    const float* img  = (const float*)d_in[0];
    const float* intr = (const float*)d_in[1];
    const int*   imw  = (const int*)d_in[2];
    const int*   imh  = (const int*)d_in[3];
    float*       out  = (float*)d_out;

    dim3 grid(NB * NC);   // one block per (b,c)
    dim3 block(512);
    hipLaunchKernelGGL(vt_kernel, grid, block, 0, stream,
                       img, intr, imw, imh, out);
}

// Round 11
// 80.549 us; speedup vs baseline: 1.6245x; 1.3094x over previous
//
#include <hip/hip_runtime.h>

#define BEVN 100
#define NB 8
#define NC 512
#define FH 88
#define FW 176
#define HWSZ (FH * FW)          // 15488 pixels per channel slice
#define NG4  (HWSZ / 4)         // 3872 uint4 groups per packed 2-channel buffer
#define G4PR (FW / 4)           // 44 groups per image row
#define NPAIR (BEVN * BEVN / 2) // 5000 cell-pairs

typedef float    f32x4 __attribute__((ext_vector_type(4)));
typedef float    f32x2 __attribute__((ext_vector_type(2)));
typedef unsigned u32x4 __attribute__((ext_vector_type(4)));

// R7 (best measured: 82.1us) + two wave-coherent work skips proven in
// R6/R8/R9: (a) rowlive[i] -> nearest BEV rows (all 3 planes y-OOB) store
// zeros with no projection/gather work at all; (b) per-plane skip for rows
// where 1-2 planes are y-OOB. Everything else byte-identical to R7.
__device__ __forceinline__ unsigned bf16rne(float f) {
    const unsigned b = __float_as_uint(f);
    return (b + 0x7fffu + ((b >> 16) & 1u)) >> 16;   // round-nearest-even
}
__device__ __forceinline__ float lo16f(unsigned u) { return __uint_as_float(u << 16); }
__device__ __forceinline__ float hi16f(unsigned u) { return __uint_as_float(u & 0xffff0000u); }

__global__ __launch_bounds__(1024, 8)
void vt_kernel(const float* __restrict__ img,
               const float* __restrict__ intr,
               const int* __restrict__ p_imw,
               const int* __restrict__ p_imh,
               float* __restrict__ out)
{
    __shared__ unsigned      buf[HWSZ];      // packed {bf16 c0 | bf16 c1<<16}
    __shared__ float4        ytab[BEVN * 3]; // {wy0/3, wy1/3, rowbase0, rowbase1}
    __shared__ unsigned char marked[FH];     // image rows needed by this b
    __shared__ unsigned char rowlive[BEVN];  // BEV rows with any valid plane

    const int blk = blockIdx.x;         // b*256 + cpair
    const int b   = blk >> 8;
    const int bc0 = b * NC + (blk & 255) * 2;
    const int tid = (int)threadIdx.x;

    const float fx  = intr[b * 9 + 0];
    const float cxv = intr[b * 9 + 2];
    const float fy  = intr[b * 9 + 4];
    const float cyv = intr[b * 9 + 5];
    const float wsc = (float)FW / (float)p_imw[0];   // 0.25
    const float hsc = (float)FH / (float)p_imh[0];   // 0.25

    if (tid < FH) marked[tid] = 0;
    if (tid < BEVN) rowlive[tid] = 0;
    __syncthreads();

    // ---- ytab + row marking + rowlive (same arithmetic -> consistent) ----
    if (tid < BEVN * 3) {
        const int   i  = tid / 3;
        const int   k  = tid - 3 * i;
        const float z  = 0.125f + 0.5f * (float)i;
        const float iz = 1.0f / z;
        const float yk = (k == 0) ? -1.0f : ((k == 1) ? 0.5f : 2.0f);
        const float yp = fmaf(fy * yk * iz + cyv, hsc, -0.5f);
        const float yf = floorf(yp);
        const int   y0 = (int)yf;
        float wy1 = yp - yf;
        float wy0 = 1.0f - wy1;
        wy0 = ((unsigned)y0 < (unsigned)FH) ? wy0 : 0.0f;
        wy1 = ((unsigned)(y0 + 1) < (unsigned)FH) ? wy1 : 0.0f;
        if (wy0 != 0.0f) marked[y0] = 1;         // y0 in [0,FH) when wy0!=0
        if (wy1 != 0.0f) marked[y0 + 1] = 1;     // y0+1 in [0,FH) when wy1!=0
        if (wy0 != 0.0f || wy1 != 0.0f) rowlive[i] = 1;
        const int yb0 = min(max(y0, 0), FH - 1) * FW;
        const int yb1 = min(max(y0 + 1, 0), FH - 1) * FW;
        float4 e;
        e.x = wy0 * (1.0f / 3.0f);
        e.y = wy1 * (1.0f / 3.0f);
        e.z = __int_as_float(yb0);
        e.w = __int_as_float(yb1);
        ytab[tid] = e;
    }
    __syncthreads();

    // ---- stage: fetch ONLY marked rows, zero-fill the rest ----
    {
        const f32x4* __restrict__ s0 = (const f32x4*)(img + (size_t)bc0 * HWSZ);
        const f32x4* __restrict__ s1 = s0 + NG4;
        u32x4* l4 = (u32x4*)buf;
        #pragma unroll
        for (int t = 0; t < 4; ++t) {
            const int g = tid + t * 1024;
            if (g < NG4) {
                u32x4 u = {0u, 0u, 0u, 0u};
                const int row = g / G4PR;            // nearly wave-uniform branch
                if (marked[row]) {
                    const f32x4 a  = __builtin_nontemporal_load(s0 + g);
                    const f32x4 bb = __builtin_nontemporal_load(s1 + g);
                    u.x = bf16rne(a.x) | (bf16rne(bb.x) << 16);
                    u.y = bf16rne(a.y) | (bf16rne(bb.y) << 16);
                    u.z = bf16rne(a.z) | (bf16rne(bb.z) << 16);
                    u.w = bf16rne(a.w) | (bf16rne(bb.w) << 16);
                }
                l4[g] = u;
            }
        }
    }
    __syncthreads();

    // x-projection: xpix = a_j * invz + bx, a_j = axb + axs*j
    const float axs = 0.5f * fx * wsc;
    const float axb = -24.875f * fx * wsc;
    const float bx  = fmaf(cxv, wsc, -0.5f);

    float* __restrict__ op0 = out + (size_t)bc0 * (BEVN * BEVN);
    float* __restrict__ op1 = op0 + (BEVN * BEVN);

    for (int p = tid; p < NPAIR; p += 1024) {
        const int i  = p / 50;               // BEV row
        const int jp = p - 50 * i;           // pair index in row

        // (a) whole-row skip: all 3 planes y-OOB -> zero output, no work
        if (!rowlive[i]) {
            const f32x2 zz = {0.0f, 0.0f};
            __builtin_nontemporal_store(zz, (f32x2*)(op0 + 2 * p));
            __builtin_nontemporal_store(zz, (f32x2*)(op1 + 2 * p));
            continue;
        }

        const float z    = fmaf(0.5f, (float)i, 0.125f);
        const float invz = __builtin_amdgcn_rcpf(z);

        int   xb[2];
        float w0[2], w1[2];
        #pragma unroll
        for (int e = 0; e < 2; ++e) {
            const float aj   = fmaf((float)(2 * jp + e), axs, axb);
            const float xpix = fmaf(aj, invz, bx);
            const float f    = floorf(xpix);
            const int   x0   = (int)f;
            float wx1 = xpix - f;
            float wx0 = 1.0f - wx1;
            wx0 = ((unsigned)x0 < (unsigned)FW) ? wx0 : 0.0f;
            wx1 = ((unsigned)(x0 + 1) < (unsigned)FW) ? wx1 : 0.0f;
            const int xbe = min(max(x0, 0), FW - 2);
            const int d   = x0 - xbe;        // 0: normal; <0: clamped up; >0: clamped down
            w0[e] = (d == 0) ? wx0 : ((d < 0) ? wx1 : 0.0f);
            w1[e] = (d == 0) ? wx1 : ((d < 0) ? 0.0f : wx0);
            xb[e] = xbe;
        }

        f32x2 rA, rB;
        const float wsum = (w0[0] + w1[0]) + (w0[1] + w1[1]);
        if (wsum == 0.0f) {
            rA = (f32x2){0.0f, 0.0f};        // whole pair OOB in x (coherent skip)
            rB = (f32x2){0.0f, 0.0f};
        } else {
            float accA[2] = {0.0f, 0.0f};
            float accB[2] = {0.0f, 0.0f};
            #pragma unroll
            for (int k = 0; k < 3; ++k) {
                const float4 e4 = ytab[i * 3 + k];
                if (e4.x != 0.0f || e4.y != 0.0f) {   // (b) per-plane y-OOB skip
                    const int yb0 = __float_as_int(e4.z);
                    const int yb1 = __float_as_int(e4.w);
                    #pragma unroll
                    for (int e = 0; e < 2; ++e) {
                        const unsigned* r0 = buf + (yb0 + xb[e]);
                        const unsigned* r1 = buf + (yb1 + xb[e]);
                        const unsigned u00 = r0[0], u01 = r0[1];   // ds_read2_b32
                        const unsigned u10 = r1[0], u11 = r1[1];   // ds_read2_b32
                        const float h0a = fmaf(w1[e], lo16f(u01), w0[e] * lo16f(u00));
                        const float h1a = fmaf(w1[e], lo16f(u11), w0[e] * lo16f(u10));
                        accA[e] = fmaf(e4.x, h0a, accA[e]);
                        accA[e] = fmaf(e4.y, h1a, accA[e]);
                        const float h0b = fmaf(w1[e], hi16f(u01), w0[e] * hi16f(u00));
                        const float h1b = fmaf(w1[e], hi16f(u11), w0[e] * hi16f(u10));
                        accB[e] = fmaf(e4.x, h0b, accB[e]);
                        accB[e] = fmaf(e4.y, h1b, accB[e]);
                    }
                }
            }
            rA = (f32x2){accA[0], accA[1]};
            rB = (f32x2){accB[0], accB[1]};
        }
        __builtin_nontemporal_store(rA, (f32x2*)(op0 + 2 * p));
        __builtin_nontemporal_store(rB, (f32x2*)(op1 + 2 * p));
    }
}

extern "C" void kernel_launch(void* const* d_in, const int* in_sizes, int n_in,
                              void* d_out, int out_size, void* d_ws, size_t ws_size,
                              hipStream_t stream) {
    const float* img  = (const float*)d_in[0];
    const float* intr = (const float*)d_in[1];
    const int*   imw  = (const int*)d_in[2];
    const int*   imh  = (const int*)d_in[3];
    float*       out  = (float*)d_out;

    dim3 grid(NB * NC / 2);   // one block per (b, channel-pair)
    dim3 block(1024);
    hipLaunchKernelGGL(vt_kernel, grid, block, 0, stream,
                       img, intr, imw, imh, out);
}